// Round 3
// baseline (975.780 us; speedup 1.0000x reference)
//
#include <hip/hip_runtime.h>

// hidden = tanh(H @ h + C @ c); comm = hidden. H,C: [64,64]; h,c: [64, 524288].
#define NA 64
#define FD 524288
#define JT 8  // j-tile: 16 batched global loads in flight per tile

// One fp32 column per thread, acc[64] in VGPRs.
//
// Round-2 post-mortem: __launch_bounds__(256,4) capped VGPR at 128 and the
// allocator SPILLED acc to scratch (VGPR_Count=56 < 64 needed; WRITE_SIZE
// +67MB of non-output traffic; dur 2.3x). Fix: (256,2) -> cap 256, actual
// use ~110-130, occupancy becomes allocator-determined (~3-5 waves/SIMD =
// 37-62%), which is enough for Little's law: ~12-16 waves/CU x 16 loads x
// 256B = 48-64KB in flight vs ~22KB needed to saturate 6.3 TB/s.
//
// Addressing: index h[row + d] off the UNIFORM base pointer so the backend
// emits global_load_dword v, v_off, s[rowbase] (row base folded to SGPRs,
// one shared VGPR offset) instead of 16 live per-lane 64-bit address pairs
// -- that address pressure is what pushed Round 2 over the cap.
__global__ __launch_bounds__(256, 2) void linlayer_kernel(
    const float* __restrict__ h, const float* __restrict__ c,
    const float* __restrict__ Hm, const float* __restrict__ Cm,
    float* __restrict__ out)
{
    const int d = blockIdx.x * blockDim.x + threadIdx.x;  // 0..524287

    float acc[NA];
#pragma unroll
    for (int i = 0; i < NA; ++i) acc[i] = 0.f;

#pragma unroll 1
    for (int jt = 0; jt < NA; jt += JT) {
        // Batched column loads: 16 dword loads in flight, coalesced
        // (lane i reads rowbase + 4*(d0+i) -> 256B/wave segments).
        float hv[JT], cv[JT];
#pragma unroll
        for (int jj = 0; jj < JT; ++jj) {
            const size_t row = (size_t)(jt + jj) * FD;
            hv[jj] = h[row + d];
            cv[jj] = c[row + d];
        }

        // FMA body: 64 i x 8 j x 2 mats = 1024 v_fmac_f32 per tile.
        // H/C rows are wave-uniform + contiguous -> s_load_dwordx4/x8;
        // v_fmac_f32 reads the SGPR operand directly (1 SGPR/instr is legal).
#pragma unroll
        for (int i = 0; i < NA; ++i) {
            float a = acc[i];
#pragma unroll
            for (int jj = 0; jj < JT; ++jj) {
                a = fmaf(Hm[i * NA + jt + jj], hv[jj], a);
                a = fmaf(Cm[i * NA + jt + jj], cv[jj], a);
            }
            acc[i] = a;
        }
    }

    // Epilogue: tanh(x) = 1 - 2/(exp(2x)+1); saturates cleanly, no NaN.
    // Non-temporal stores keep the 268MB output stream from evicting the
    // input set from L2/L3 (inputs stay warm across bench re-dispatches;
    // Round-0 FETCH was 135MB < 256MB input size for exactly this reason).
#pragma unroll
    for (int i = 0; i < NA; ++i) {
        const float e = __expf(2.0f * acc[i]);
        const float t = 1.0f - 2.0f / (e + 1.0f);
        __builtin_nontemporal_store(t, &out[(size_t)i * FD + d]);        // hidden
        __builtin_nontemporal_store(t, &out[(size_t)(NA + i) * FD + d]); // comm
    }
}

extern "C" void kernel_launch(void* const* d_in, const int* in_sizes, int n_in,
                              void* d_out, int out_size, void* d_ws, size_t ws_size,
                              hipStream_t stream) {
    const float* h  = (const float*)d_in[0];
    const float* c  = (const float*)d_in[1];
    const float* Hm = (const float*)d_in[2];
    const float* Cm = (const float*)d_in[3];
    float* out = (float*)d_out;

    dim3 block(256);
    dim3 grid(FD / 256);  // 2048 blocks; every thread owns one fp32 column
    hipLaunchKernelGGL(linlayer_kernel, grid, block, 0, stream,
                       h, c, Hm, Cm, out);
}

// Round 4
// 488.848 us; speedup vs baseline: 1.9961x; 1.9961x over previous
//
#include <hip/hip_runtime.h>

// hidden = tanh(H @ h + C @ c); comm = hidden. H,C: [64,64]; h,c: [64, 524288].
#define NA 64
#define FD 524288
#define FD2 (FD / 2)   // 262144 float2 columns
#define ROWS 16        // output rows per wave (4 waves/block cover all 64)

// Round-0 structure (proven VALU-clean, spill-free) with the i-dimension
// split across the block's 4 waves: acc[16] float2 = 32 VGPR (vs 128), so
// total VGPR ~56-72 -> 7-8 waves/SIMD (~28-32 waves/CU vs Round 0's 7).
// That is the Little's-law fix: ~30 KB/CU of loads in flight vs 8 KB.
//
// The 4 waves re-read the same h/c cache lines; they run near-lockstep so
// the extra 3x requests hit L1/L2 (L2 ceiling 34.5 TB/s >> demand). HBM
// traffic stays 1x input + 1x output.
//
// Per-j coefficient working set is 32 floats (16 rows x {H,C}) -> fits
// SGPRs; i0 is forced scalar with readfirstlane so H/C reads stay s_load
// (the Round-2/3 regression was this pattern collapsing into per-lane
// vector loads when 1024 coefficients went live per tile).
__global__ __launch_bounds__(256) void linlayer_kernel(
    const float* __restrict__ h, const float* __restrict__ c,
    const float* __restrict__ Hm, const float* __restrict__ Cm,
    float* __restrict__ out)
{
    const int lane = threadIdx.x & 63;
    int i0 = (threadIdx.x >> 6) * ROWS;          // wave-uniform
    i0 = __builtin_amdgcn_readfirstlane(i0);     // force SGPR

    const int col2 = blockIdx.x * 64 + lane;     // this thread's float2 column

    const float2* __restrict__ h2 = (const float2*)h;
    const float2* __restrict__ c2 = (const float2*)c;
    float2* __restrict__ o2 = (float2*)out;

    const float* __restrict__ Hr = Hm + i0 * NA; // scalar row base
    const float* __restrict__ Cr = Cm + i0 * NA;

    float2 acc[ROWS];
#pragma unroll
    for (int i = 0; i < ROWS; ++i) { acc[i].x = 0.f; acc[i].y = 0.f; }

    // 1-deep software pipeline (Round-0 pattern): hv/cv = row j, hn/cn = j+1.
    float2 hv = h2[col2];
    float2 cv = c2[col2];

#pragma unroll 1
    for (int j = 0; j < NA; ++j) {
        const int jn = (j + 1) & (NA - 1);       // clamped wrap, no branch
        const float2 hn = h2[(size_t)jn * FD2 + col2];
        const float2 cn = c2[(size_t)jn * FD2 + col2];
#pragma unroll
        for (int i = 0; i < ROWS; ++i) {
            const float Hij = Hr[i * NA + j];    // s_load, imm offset i*256
            const float Cij = Cr[i * NA + j];
            acc[i].x = fmaf(Hij, hv.x, fmaf(Cij, cv.x, acc[i].x));
            acc[i].y = fmaf(Hij, hv.y, fmaf(Cij, cv.y, acc[i].y));
        }
        hv = hn; cv = cn;
    }

    // tanh(x) = 1 - 2/(exp(2x)+1); saturates cleanly, no NaN. Plain stores
    // (Round 0's L3 input-retention behavior was with plain stores; the NT
    // experiment showed no fetch benefit).
#pragma unroll
    for (int i = 0; i < ROWS; ++i) {
        float2 t;
        { const float e = __expf(2.0f * acc[i].x); t.x = 1.0f - 2.0f / (e + 1.0f); }
        { const float e = __expf(2.0f * acc[i].y); t.y = 1.0f - 2.0f / (e + 1.0f); }
        o2[(size_t)(i0 + i) * FD2 + col2] = t;         // hidden
        o2[(size_t)(NA + i0 + i) * FD2 + col2] = t;    // comm (same values)
    }
}

extern "C" void kernel_launch(void* const* d_in, const int* in_sizes, int n_in,
                              void* d_out, int out_size, void* d_ws, size_t ws_size,
                              hipStream_t stream) {
    const float* h  = (const float*)d_in[0];
    const float* c  = (const float*)d_in[1];
    const float* Hm = (const float*)d_in[2];
    const float* Cm = (const float*)d_in[3];
    float* out = (float*)d_out;

    dim3 block(256);
    dim3 grid(FD2 / 64);  // 4096 blocks; block covers 64 float2 cols x all 64 rows
    hipLaunchKernelGGL(linlayer_kernel, grid, block, 0, stream,
                       h, c, Hm, Cm, out);
}